// Round 1
// baseline (514.971 us; speedup 1.0000x reference)
//
#include <hip/hip_runtime.h>
#include <hip/hip_bf16.h>

#define CDIM 384
#define NHEAD 6
#define DHEAD 64
#define BB 16
#define NQ 1024
#define MV 512
#define HIDD 1536
#define KNN 10

typedef __attribute__((ext_vector_type(8))) __bf16 bf16x8;
typedef __attribute__((ext_vector_type(4))) float f32x4;

// ---------------- weight transpose-cast: Wt[n][k] = W[k][n] (f32 -> bf16) ----------------
__global__ void cast_t_kernel(const float* __restrict__ W, __hip_bfloat16* __restrict__ Wt,
                              int Kd, int Nd) {
  __shared__ float tile[32][33];
  int k0 = blockIdx.x * 32, n0 = blockIdx.y * 32;
  int tx = threadIdx.x, ty = threadIdx.y;
#pragma unroll
  for (int i = 0; i < 4; i++)
    tile[ty + i * 8][tx] = W[(size_t)(k0 + ty + i * 8) * Nd + n0 + tx];
  __syncthreads();
#pragma unroll
  for (int i = 0; i < 4; i++)
    Wt[(size_t)(n0 + ty + i * 8) * Kd + k0 + tx] = __float2bfloat16(tile[tx][ty + i * 8]);
}

// knn_w (768x384): W1t[n][k]=knn[k][n]; Wdt[n][k]=knn[384+k][n]-knn[k][n]
__global__ void cast_t_knn_kernel(const float* __restrict__ Wk,
                                  __hip_bfloat16* __restrict__ W1t,
                                  __hip_bfloat16* __restrict__ Wdt) {
  __shared__ float t1[32][33];
  __shared__ float t2[32][33];
  int k0 = blockIdx.x * 32, n0 = blockIdx.y * 32;
  int tx = threadIdx.x, ty = threadIdx.y;
#pragma unroll
  for (int i = 0; i < 4; i++) {
    int k = k0 + ty + i * 8;
    float w1 = Wk[(size_t)k * CDIM + n0 + tx];
    float w2 = Wk[(size_t)(CDIM + k) * CDIM + n0 + tx];
    t1[ty + i * 8][tx] = w1;
    t2[ty + i * 8][tx] = w2 - w1;
  }
  __syncthreads();
#pragma unroll
  for (int i = 0; i < 4; i++) {
    W1t[(size_t)(n0 + ty + i * 8) * CDIM + k0 + tx] = __float2bfloat16(t1[tx][ty + i * 8]);
    Wdt[(size_t)(n0 + ty + i * 8) * CDIM + k0 + tx] = __float2bfloat16(t2[tx][ty + i * 8]);
  }
}

// ---------------- LayerNorm: f32 in -> bf16 out, 384 cols, one wave per row -------------
__global__ __launch_bounds__(256) void ln_kernel(const float* __restrict__ x,
                                                 const float* __restrict__ gw,
                                                 const float* __restrict__ bw,
                                                 __hip_bfloat16* __restrict__ out, int rows) {
  int wave = (int)((blockIdx.x * blockDim.x + threadIdx.x) >> 6);
  int lane = threadIdx.x & 63;
  if (wave >= rows) return;
  const float* xr = x + (size_t)wave * CDIM;
  float v0[6];
  float s = 0.f;
#pragma unroll
  for (int i = 0; i < 3; i++) {
    float2 t = *reinterpret_cast<const float2*>(xr + i * 128 + lane * 2);
    v0[i * 2] = t.x; v0[i * 2 + 1] = t.y; s += t.x + t.y;
  }
  for (int off = 32; off; off >>= 1) s += __shfl_xor(s, off);
  float mean = s * (1.f / 384.f);
  float sq = 0.f;
#pragma unroll
  for (int i = 0; i < 6; i++) { float d = v0[i] - mean; sq += d * d; }
  for (int off = 32; off; off >>= 1) sq += __shfl_xor(sq, off);
  float rstd = rsqrtf(sq * (1.f / 384.f) + 1e-5f);
#pragma unroll
  for (int i = 0; i < 3; i++) {
    int c = i * 128 + lane * 2;
    float2 gg = *reinterpret_cast<const float2*>(gw + c);
    float2 bb = *reinterpret_cast<const float2*>(bw + c);
    float o0 = (v0[i * 2] - mean) * rstd * gg.x + bb.x;
    float o1 = (v0[i * 2 + 1] - mean) * rstd * gg.y + bb.y;
    __hip_bfloat162 p;
    p.x = __float2bfloat16(o0); p.y = __float2bfloat16(o1);
    *reinterpret_cast<__hip_bfloat162*>(out + (size_t)wave * CDIM + c) = p;
  }
}

// ---------------- generic bf16 GEMM: A(MxK) @ Bt(NxK)^T, 64x64 tile, 4 waves ------------
// EPI: 0 plain->bf16 | 1 bias->f32 | 2 bias+resid->f32 | 3 bias+gelu->bf16 | 4 plain->f32
template <int EPI>
__global__ __launch_bounds__(256) void gemm_kernel(const __hip_bfloat16* __restrict__ A,
                                                   const __hip_bfloat16* __restrict__ Bt,
                                                   const float* __restrict__ bias,
                                                   const float* __restrict__ resid,
                                                   void* __restrict__ outp,
                                                   int M, int N, int Kdim) {
  __shared__ __align__(16) __hip_bfloat16 As[64][72];
  __shared__ __align__(16) __hip_bfloat16 Bs[64][72];
  int m0 = blockIdx.y * 64, n0 = blockIdx.x * 64;
  int t = threadIdx.x;
  int lane = t & 63, w = t >> 6;
  int wrow = w >> 1, wcol = w & 1;
  int lg = lane >> 4, lr = lane & 15;
  f32x4 acc[2][2] = {};
  int ldRow = t >> 3;
  int ldCol = (t & 7) * 8;
  for (int k0 = 0; k0 < Kdim; k0 += 64) {
    __syncthreads();
#pragma unroll
    for (int i = 0; i < 2; i++) {
      int r = ldRow + i * 32;
      *reinterpret_cast<uint4*>(&As[r][ldCol]) =
          *reinterpret_cast<const uint4*>(A + (size_t)(m0 + r) * Kdim + k0 + ldCol);
      *reinterpret_cast<uint4*>(&Bs[r][ldCol]) =
          *reinterpret_cast<const uint4*>(Bt + (size_t)(n0 + r) * Kdim + k0 + ldCol);
    }
    __syncthreads();
#pragma unroll
    for (int kk = 0; kk < 2; kk++) {
      bf16x8 a[2], b[2];
#pragma unroll
      for (int i = 0; i < 2; i++) {
        a[i] = *reinterpret_cast<const bf16x8*>(&As[wrow * 32 + i * 16 + lr][kk * 32 + lg * 8]);
        b[i] = *reinterpret_cast<const bf16x8*>(&Bs[wcol * 32 + i * 16 + lr][kk * 32 + lg * 8]);
      }
#pragma unroll
      for (int i = 0; i < 2; i++)
#pragma unroll
        for (int j = 0; j < 2; j++)
          acc[i][j] = __builtin_amdgcn_mfma_f32_16x16x32_bf16(a[i], b[j], acc[i][j], 0, 0, 0);
    }
  }
#pragma unroll
  for (int i = 0; i < 2; i++)
#pragma unroll
    for (int j = 0; j < 2; j++) {
      int col = n0 + wcol * 32 + j * 16 + lr;
#pragma unroll
      for (int r = 0; r < 4; r++) {
        int row = m0 + wrow * 32 + i * 16 + lg * 4 + r;
        float v = acc[i][j][r];
        if (EPI == 1 || EPI == 2 || EPI == 3) v += bias[col];
        if (EPI == 2) v += resid[(size_t)row * N + col];
        if (EPI == 3) v = 0.5f * v * (1.f + erff(v * 0.70710678118654752f));
        if (EPI == 0 || EPI == 3)
          ((__hip_bfloat16*)outp)[(size_t)row * N + col] = __float2bfloat16(v);
        else
          ((float*)outp)[(size_t)row * N + col] = v;
      }
    }
}

// ---------------- repack qkv -> Qb(scaled)/Kb and transposed Vt -------------------------
__global__ __launch_bounds__(256) void repack_qk_kernel(const __hip_bfloat16* __restrict__ qkv,
                                                        __hip_bfloat16* __restrict__ Qb,
                                                        __hip_bfloat16* __restrict__ Kb) {
  int u = blockIdx.x * blockDim.x + threadIdx.x;  // 16384*48 units
  int row = u / 48, seg = u % 48;
  int col = seg * 8;
  int h = col >> 6, d = col & 63;
  int b = row >> 10, n = row & 1023;
  size_t src = (size_t)row * (3 * CDIM);
  size_t dst = (((size_t)(b * NHEAD + h)) * NQ + n) * DHEAD + d;
  union U { uint4 v; __hip_bfloat16 h[8]; };
  U qu, qo;
  qu.v = *reinterpret_cast<const uint4*>(qkv + src + col);
#pragma unroll
  for (int j = 0; j < 8; j++) qo.h[j] = __float2bfloat16(__bfloat162float(qu.h[j]) * 0.125f);
  *reinterpret_cast<uint4*>(Qb + dst) = qo.v;
  *reinterpret_cast<uint4*>(Kb + dst) =
      *reinterpret_cast<const uint4*>(qkv + src + CDIM + col);
}

__global__ void repack_v_kernel(const __hip_bfloat16* __restrict__ qkv,
                                __hip_bfloat16* __restrict__ Vt) {
  __shared__ __hip_bfloat16 tile[32][33];
  int bh = blockIdx.z;
  int b = bh / NHEAD, h = bh % NHEAD;
  int n0 = blockIdx.x * 32, d0 = blockIdx.y * 32;
  int tx = threadIdx.x, ty = threadIdx.y;
#pragma unroll
  for (int i = 0; i < 4; i++) {
    int n = n0 + ty + i * 8;
    tile[ty + i * 8][tx] = qkv[((size_t)(b * NQ + n)) * (3 * CDIM) + 2 * CDIM + h * DHEAD + d0 + tx];
  }
  __syncthreads();
#pragma unroll
  for (int i = 0; i < 4; i++) {
    int d = d0 + ty + i * 8;
    Vt[((size_t)bh * DHEAD + d) * NQ + n0 + tx] = tile[tx][ty + i * 8];
  }
}

// ---------------- flash attention: wave = 16 q-rows, kv tiles of 32 ---------------------
__global__ __launch_bounds__(256) void attn_kernel(const __hip_bfloat16* __restrict__ Qb,
                                                   const __hip_bfloat16* __restrict__ Kb,
                                                   const __hip_bfloat16* __restrict__ Vt,
                                                   __hip_bfloat16* __restrict__ SAb) {
  __shared__ __align__(16) __hip_bfloat16 Plds[4][16][32];
  int bh = blockIdx.x >> 4;
  int tile = blockIdx.x & 15;
  int w = threadIdx.x >> 6, lane = threadIdx.x & 63;
  int lg = lane >> 4, lr = lane & 15;
  int q0 = tile * 64 + w * 16;
  const __hip_bfloat16* Qp = Qb + (size_t)bh * NQ * DHEAD;
  const __hip_bfloat16* Kp = Kb + (size_t)bh * NQ * DHEAD;
  const __hip_bfloat16* Vp = Vt + (size_t)bh * DHEAD * NQ;
  bf16x8 qf0 = *reinterpret_cast<const bf16x8*>(Qp + (size_t)(q0 + lr) * DHEAD + lg * 8);
  bf16x8 qf1 = *reinterpret_cast<const bf16x8*>(Qp + (size_t)(q0 + lr) * DHEAD + 32 + lg * 8);
  f32x4 o[4] = {};
  float mrun[4], lrun[4];
#pragma unroll
  for (int r = 0; r < 4; r++) { mrun[r] = -1e30f; lrun[r] = 0.f; }
  for (int kt = 0; kt < 32; kt++) {
    int kb = kt * 32;
    f32x4 s0 = {}, s1 = {};
    bf16x8 kf;
    kf = *reinterpret_cast<const bf16x8*>(Kp + (size_t)(kb + lr) * DHEAD + lg * 8);
    s0 = __builtin_amdgcn_mfma_f32_16x16x32_bf16(qf0, kf, s0, 0, 0, 0);
    kf = *reinterpret_cast<const bf16x8*>(Kp + (size_t)(kb + lr) * DHEAD + 32 + lg * 8);
    s0 = __builtin_amdgcn_mfma_f32_16x16x32_bf16(qf1, kf, s0, 0, 0, 0);
    kf = *reinterpret_cast<const bf16x8*>(Kp + (size_t)(kb + 16 + lr) * DHEAD + lg * 8);
    s1 = __builtin_amdgcn_mfma_f32_16x16x32_bf16(qf0, kf, s1, 0, 0, 0);
    kf = *reinterpret_cast<const bf16x8*>(Kp + (size_t)(kb + 16 + lr) * DHEAD + 32 + lg * 8);
    s1 = __builtin_amdgcn_mfma_f32_16x16x32_bf16(qf1, kf, s1, 0, 0, 0);
    float p0s[4], p1s[4];
#pragma unroll
    for (int r = 0; r < 4; r++) {
      float tm = fmaxf(s0[r], s1[r]);
      tm = fmaxf(tm, __shfl_xor(tm, 1));
      tm = fmaxf(tm, __shfl_xor(tm, 2));
      tm = fmaxf(tm, __shfl_xor(tm, 4));
      tm = fmaxf(tm, __shfl_xor(tm, 8));
      float mn = fmaxf(mrun[r], tm);
      float corr = __expf(mrun[r] - mn);
      float p0 = __expf(s0[r] - mn);
      float p1 = __expf(s1[r] - mn);
      float ps = p0 + p1;
      ps += __shfl_xor(ps, 1); ps += __shfl_xor(ps, 2);
      ps += __shfl_xor(ps, 4); ps += __shfl_xor(ps, 8);
      lrun[r] = lrun[r] * corr + ps;
      mrun[r] = mn;
#pragma unroll
      for (int dt = 0; dt < 4; dt++) o[dt][r] *= corr;
      p0s[r] = p0; p1s[r] = p1;
    }
#pragma unroll
    for (int r = 0; r < 4; r++) {
      Plds[w][lg * 4 + r][lr] = __float2bfloat16(p0s[r]);
      Plds[w][lg * 4 + r][16 + lr] = __float2bfloat16(p1s[r]);
    }
    __syncthreads();
    bf16x8 pa = *reinterpret_cast<const bf16x8*>(&Plds[w][lr][lg * 8]);
#pragma unroll
    for (int dt = 0; dt < 4; dt++) {
      bf16x8 vf = *reinterpret_cast<const bf16x8*>(Vp + (size_t)(dt * 16 + lr) * NQ + kb + lg * 8);
      o[dt] = __builtin_amdgcn_mfma_f32_16x16x32_bf16(pa, vf, o[dt], 0, 0, 0);
    }
    __syncthreads();
  }
  int b = bh / NHEAD, h = bh % NHEAD;
#pragma unroll
  for (int dt = 0; dt < 4; dt++)
#pragma unroll
    for (int r = 0; r < 4; r++) {
      int row = q0 + lg * 4 + r;
      float val = o[dt][r] / lrun[r];
      SAb[((size_t)(b * NQ + row)) * CDIM + h * DHEAD + dt * 16 + lr] = __float2bfloat16(val);
    }
}

// ---------------- top-K (K=10) nearest of 512 in f64, wave per query --------------------
__global__ __launch_bounds__(256) void topk_kernel(const float* __restrict__ q_pos,
                                                   const float* __restrict__ v_pos,
                                                   int* __restrict__ idxb) {
  int wq = (int)((blockIdx.x * blockDim.x + threadIdx.x) >> 6);
  int lane = threadIdx.x & 63;
  if (wq >= BB * NQ) return;
  int b = wq >> 10;
  const float* qp = q_pos + (size_t)wq * 3;
  double qx = qp[0], qy = qp[1], qz = qp[2];
  double qs = qx * qx + qy * qy + qz * qz;
  double dloc[8];
#pragma unroll
  for (int j = 0; j < 8; j++) {
    int m = lane + 64 * j;
    const float* vp = v_pos + ((size_t)b * MV + m) * 3;
    double vx = vp[0], vy = vp[1], vz = vp[2];
    double vs = vx * vx + vy * vy + vz * vz;
    dloc[j] = qs + vs - 2.0 * (qx * vx + qy * vy + qz * vz);
  }
  for (int k = 0; k < KNN; k++) {
    double best = dloc[0];
    int bj = 0;
#pragma unroll
    for (int j = 1; j < 8; j++)
      if (dloc[j] < best) { best = dloc[j]; bj = j; }
    int bm = lane + 64 * bj;
    for (int off = 1; off < 64; off <<= 1) {
      double od = __shfl_xor(best, off);
      int om = __shfl_xor(bm, off);
      if (od < best || (od == best && om < bm)) { best = od; bm = om; }
    }
    if (lane == 0) idxb[wq * KNN + k] = bm;
#pragma unroll
    for (int j = 0; j < 8; j++)
      if (bm == lane + 64 * j) dloc[j] = 1e300;
  }
}

// ---------------- gather + leaky_relu + max over K + residual ---------------------------
__global__ __launch_bounds__(256) void gather_max_kernel(const float* __restrict__ A1,
                                                         const float* __restrict__ A2,
                                                         const float* __restrict__ q1,
                                                         const int* __restrict__ idxb,
                                                         float* __restrict__ q2) {
  int wq = (int)((blockIdx.x * blockDim.x + threadIdx.x) >> 6);
  int lane = threadIdx.x & 63;
  if (wq >= BB * NQ) return;
  int b = wq >> 10;
  float a2[6], mx[6];
#pragma unroll
  for (int i = 0; i < 6; i++) {
    a2[i] = A2[(size_t)wq * CDIM + lane + 64 * i];
    mx[i] = -1e30f;
  }
  for (int k = 0; k < KNN; k++) {
    int id = idxb[wq * KNN + k];
    const float* a1 = A1 + ((size_t)b * MV + id) * CDIM;
#pragma unroll
    for (int i = 0; i < 6; i++) {
      float g = a1[lane + 64 * i] + a2[i];
      g = g > 0.f ? g : 0.2f * g;
      mx[i] = fmaxf(mx[i], g);
    }
  }
#pragma unroll
  for (int i = 0; i < 6; i++) {
    int c = lane + 64 * i;
    q2[(size_t)wq * CDIM + c] = q1[(size_t)wq * CDIM + c] + mx[i];
  }
}

// ---------------------------------- launcher --------------------------------------------
extern "C" void kernel_launch(void* const* d_in, const int* in_sizes, int n_in,
                              void* d_out, int out_size, void* d_ws, size_t ws_size,
                              hipStream_t stream) {
  const float* q = (const float*)d_in[0];
  const float* v = (const float*)d_in[1];
  const float* q_pos = (const float*)d_in[2];
  const float* v_pos = (const float*)d_in[3];
  const float* norm1_g = (const float*)d_in[4];
  const float* norm1_b = (const float*)d_in[5];
  const float* qkv_w = (const float*)d_in[6];
  const float* proj_w = (const float*)d_in[7];
  const float* proj_b = (const float*)d_in[8];
  const float* normq_g = (const float*)d_in[9];
  const float* normq_b = (const float*)d_in[10];
  const float* normv_g = (const float*)d_in[11];
  const float* normv_b = (const float*)d_in[12];
  const float* knn_w = (const float*)d_in[13];
  const float* knn_b = (const float*)d_in[14];
  const float* norm2_g = (const float*)d_in[15];
  const float* norm2_b = (const float*)d_in[16];
  const float* fc1_w = (const float*)d_in[17];
  const float* fc1_b = (const float*)d_in[18];
  const float* fc2_w = (const float*)d_in[19];
  const float* fc2_b = (const float*)d_in[20];

  char* ws = (char*)d_ws;
  const size_t SZ_Wqkv = (size_t)1152 * 384 * 2;
  const size_t SZ_W384 = (size_t)384 * 384 * 2;
  const size_t SZ_Wfc = (size_t)1536 * 384 * 2;
  const size_t SZ_Xbf = (size_t)16384 * 384 * 2;
  const size_t SZ_QKV = (size_t)16384 * 1152 * 2;
  const size_t SZ_q32 = (size_t)16384 * 384 * 4;
  const size_t SZ_NV = (size_t)8192 * 384 * 2;

  size_t o_Wqkv = 0;
  size_t o_Wproj = o_Wqkv + SZ_Wqkv;
  size_t o_W1 = o_Wproj + SZ_W384;
  size_t o_Wd = o_W1 + SZ_W384;
  size_t o_Wfc1 = o_Wd + SZ_W384;
  size_t o_Wfc2 = o_Wfc1 + SZ_Wfc;
  size_t o_Xbf = o_Wfc2 + SZ_Wfc;
  size_t o_QKV = o_Xbf + SZ_Xbf;       // later reused: A1f (f32) and A2f (f32)
  size_t o_A1 = o_QKV;
  size_t o_A2 = o_QKV + (size_t)8192 * 384 * 4;
  size_t o_Qb = o_QKV + SZ_QKV;
  size_t o_Kb = o_Qb + SZ_Xbf;
  size_t o_Vt = o_Kb + SZ_Xbf;
  size_t o_SA = o_Vt + SZ_Xbf;
  size_t o_H1 = o_Qb;                  // reuse Qb..SA (exactly 16384*1536*2 bytes)
  size_t o_q1 = o_SA + SZ_Xbf;
  size_t o_NV = o_q1 + SZ_q32;
  size_t o_q2 = o_NV + SZ_NV;
  size_t o_idx = o_q2 + SZ_q32;

  __hip_bfloat16* Wqkv_t = (__hip_bfloat16*)(ws + o_Wqkv);
  __hip_bfloat16* Wproj_t = (__hip_bfloat16*)(ws + o_Wproj);
  __hip_bfloat16* W1_t = (__hip_bfloat16*)(ws + o_W1);
  __hip_bfloat16* Wd_t = (__hip_bfloat16*)(ws + o_Wd);
  __hip_bfloat16* Wfc1_t = (__hip_bfloat16*)(ws + o_Wfc1);
  __hip_bfloat16* Wfc2_t = (__hip_bfloat16*)(ws + o_Wfc2);
  __hip_bfloat16* Xbf = (__hip_bfloat16*)(ws + o_Xbf);
  __hip_bfloat16* QKVb = (__hip_bfloat16*)(ws + o_QKV);
  float* A1f = (float*)(ws + o_A1);
  float* A2f = (float*)(ws + o_A2);
  __hip_bfloat16* Qb = (__hip_bfloat16*)(ws + o_Qb);
  __hip_bfloat16* Kb = (__hip_bfloat16*)(ws + o_Kb);
  __hip_bfloat16* Vt = (__hip_bfloat16*)(ws + o_Vt);
  __hip_bfloat16* SAb = (__hip_bfloat16*)(ws + o_SA);
  __hip_bfloat16* H1 = (__hip_bfloat16*)(ws + o_H1);
  float* q1 = (float*)(ws + o_q1);
  __hip_bfloat16* NV = (__hip_bfloat16*)(ws + o_NV);
  float* q2 = (float*)(ws + o_q2);
  int* idxb = (int*)(ws + o_idx);
  float* outf = (float*)d_out;

  dim3 b32x8(32, 8);
  // 1. weights
  cast_t_kernel<<<dim3(12, 36), b32x8, 0, stream>>>(qkv_w, Wqkv_t, 384, 1152);
  cast_t_kernel<<<dim3(12, 12), b32x8, 0, stream>>>(proj_w, Wproj_t, 384, 384);
  cast_t_knn_kernel<<<dim3(12, 12), b32x8, 0, stream>>>(knn_w, W1_t, Wd_t);
  cast_t_kernel<<<dim3(12, 48), b32x8, 0, stream>>>(fc1_w, Wfc1_t, 384, 1536);
  cast_t_kernel<<<dim3(48, 12), b32x8, 0, stream>>>(fc2_w, Wfc2_t, 1536, 384);
  // 2. LN1(q)
  ln_kernel<<<4096, 256, 0, stream>>>(q, norm1_g, norm1_b, Xbf, 16384);
  // 3. qkv gemm
  gemm_kernel<0><<<dim3(18, 256), 256, 0, stream>>>(Xbf, Wqkv_t, nullptr, nullptr, QKVb,
                                                    16384, 1152, 384);
  // 4. repack
  repack_qk_kernel<<<3072, 256, 0, stream>>>(QKVb, Qb, Kb);
  repack_v_kernel<<<dim3(32, 2, 96), b32x8, 0, stream>>>(QKVb, Vt);
  // 5. attention
  attn_kernel<<<1536, 256, 0, stream>>>(Qb, Kb, Vt, SAb);
  // 6. proj + bias + residual(q) -> q1
  gemm_kernel<2><<<dim3(6, 256), 256, 0, stream>>>(SAb, Wproj_t, proj_b, q, q1, 16384, 384, 384);
  // 7. LN(q1)->NQ(Xbf), LN(v)->NV
  ln_kernel<<<4096, 256, 0, stream>>>(q1, normq_g, normq_b, Xbf, 16384);
  ln_kernel<<<2048, 256, 0, stream>>>(v, normv_g, normv_b, NV, 8192);
  // 8. A1 = NV@W1
  gemm_kernel<4><<<dim3(6, 128), 256, 0, stream>>>(NV, W1_t, nullptr, nullptr, A1f, 8192, 384, 384);
  // 9. A2 = NQ@Wd + knn_b
  gemm_kernel<1><<<dim3(6, 256), 256, 0, stream>>>(Xbf, Wd_t, knn_b, nullptr, A2f, 16384, 384, 384);
  // 10. top-k
  topk_kernel<<<4096, 256, 0, stream>>>(q_pos, v_pos, idxb);
  // 11. gather/max/residual -> q2
  gather_max_kernel<<<4096, 256, 0, stream>>>(A1f, A2f, q1, idxb, q2);
  // 12. LN2(q2)->Xbf
  ln_kernel<<<4096, 256, 0, stream>>>(q2, norm2_g, norm2_b, Xbf, 16384);
  // 13. fc1 + gelu -> H1
  gemm_kernel<3><<<dim3(24, 256), 256, 0, stream>>>(Xbf, Wfc1_t, fc1_b, nullptr, H1,
                                                    16384, 1536, 384);
  // 14. fc2 + bias + residual(q2) -> out
  gemm_kernel<2><<<dim3(6, 256), 256, 0, stream>>>(H1, Wfc2_t, fc2_b, q2, outf, 16384, 384, 1536);
}

// Round 2
// 368.574 us; speedup vs baseline: 1.3972x; 1.3972x over previous
//
#include <hip/hip_runtime.h>
#include <hip/hip_bf16.h>

#define CDIM 384
#define NHEAD 6
#define DHEAD 64
#define BB 16
#define NQ 1024
#define MV 512
#define HIDD 1536
#define KNN 10

typedef __attribute__((ext_vector_type(8))) __bf16 bf16x8;
typedef __attribute__((ext_vector_type(4))) float f32x4;
typedef __attribute__((ext_vector_type(4))) short short4v;

// ---------------- weight transpose-cast: Wt[n][k] = W[k][n] (f32 -> bf16) ----------------
__global__ void cast_t_kernel(const float* __restrict__ W, __hip_bfloat16* __restrict__ Wt,
                              int Kd, int Nd) {
  __shared__ float tile[32][33];
  int k0 = blockIdx.x * 32, n0 = blockIdx.y * 32;
  int tx = threadIdx.x, ty = threadIdx.y;
#pragma unroll
  for (int i = 0; i < 4; i++)
    tile[ty + i * 8][tx] = W[(size_t)(k0 + ty + i * 8) * Nd + n0 + tx];
  __syncthreads();
#pragma unroll
  for (int i = 0; i < 4; i++)
    Wt[(size_t)(n0 + ty + i * 8) * Kd + k0 + tx] = __float2bfloat16(tile[tx][ty + i * 8]);
}

// knn_w (768x384): W1t[n][k]=knn[k][n]; Wdt[n][k]=knn[384+k][n]-knn[k][n]
__global__ void cast_t_knn_kernel(const float* __restrict__ Wk,
                                  __hip_bfloat16* __restrict__ W1t,
                                  __hip_bfloat16* __restrict__ Wdt) {
  __shared__ float t1[32][33];
  __shared__ float t2[32][33];
  int k0 = blockIdx.x * 32, n0 = blockIdx.y * 32;
  int tx = threadIdx.x, ty = threadIdx.y;
#pragma unroll
  for (int i = 0; i < 4; i++) {
    int k = k0 + ty + i * 8;
    float w1 = Wk[(size_t)k * CDIM + n0 + tx];
    float w2 = Wk[(size_t)(CDIM + k) * CDIM + n0 + tx];
    t1[ty + i * 8][tx] = w1;
    t2[ty + i * 8][tx] = w2 - w1;
  }
  __syncthreads();
#pragma unroll
  for (int i = 0; i < 4; i++) {
    W1t[(size_t)(n0 + ty + i * 8) * CDIM + k0 + tx] = __float2bfloat16(t1[tx][ty + i * 8]);
    Wdt[(size_t)(n0 + ty + i * 8) * CDIM + k0 + tx] = __float2bfloat16(t2[tx][ty + i * 8]);
  }
}

// ---------------- LayerNorm: f32 in -> bf16 out, 384 cols, one wave per row -------------
__global__ __launch_bounds__(256) void ln_kernel(const float* __restrict__ x,
                                                 const float* __restrict__ gw,
                                                 const float* __restrict__ bw,
                                                 __hip_bfloat16* __restrict__ out, int rows) {
  int wave = (int)((blockIdx.x * blockDim.x + threadIdx.x) >> 6);
  int lane = threadIdx.x & 63;
  if (wave >= rows) return;
  const float* xr = x + (size_t)wave * CDIM;
  float v0[6];
  float s = 0.f;
#pragma unroll
  for (int i = 0; i < 3; i++) {
    float2 t = *reinterpret_cast<const float2*>(xr + i * 128 + lane * 2);
    v0[i * 2] = t.x; v0[i * 2 + 1] = t.y; s += t.x + t.y;
  }
  for (int off = 32; off; off >>= 1) s += __shfl_xor(s, off);
  float mean = s * (1.f / 384.f);
  float sq = 0.f;
#pragma unroll
  for (int i = 0; i < 6; i++) { float d = v0[i] - mean; sq += d * d; }
  for (int off = 32; off; off >>= 1) sq += __shfl_xor(sq, off);
  float rstd = rsqrtf(sq * (1.f / 384.f) + 1e-5f);
#pragma unroll
  for (int i = 0; i < 3; i++) {
    int c = i * 128 + lane * 2;
    float2 gg = *reinterpret_cast<const float2*>(gw + c);
    float2 bb = *reinterpret_cast<const float2*>(bw + c);
    float o0 = (v0[i * 2] - mean) * rstd * gg.x + bb.x;
    float o1 = (v0[i * 2 + 1] - mean) * rstd * gg.y + bb.y;
    __hip_bfloat162 p;
    p.x = __float2bfloat16(o0); p.y = __float2bfloat16(o1);
    *reinterpret_cast<__hip_bfloat162*>(out + (size_t)wave * CDIM + c) = p;
  }
}

// ---------------- generic bf16 GEMM: A(MxK) @ Bt(NxK)^T, 64x64 tile, 4 waves ------------
// EPI: 0 plain->bf16 | 1 bias->f32 | 2 bias+resid->f32 | 3 bias+gelu->bf16 | 4 plain->f32
template <int EPI>
__global__ __launch_bounds__(256) void gemm_kernel(const __hip_bfloat16* __restrict__ A,
                                                   const __hip_bfloat16* __restrict__ Bt,
                                                   const float* __restrict__ bias,
                                                   const float* __restrict__ resid,
                                                   void* __restrict__ outp,
                                                   int M, int N, int Kdim) {
  __shared__ __align__(16) __hip_bfloat16 As[64][72];
  __shared__ __align__(16) __hip_bfloat16 Bs[64][72];
  int m0 = blockIdx.y * 64, n0 = blockIdx.x * 64;
  int t = threadIdx.x;
  int lane = t & 63, w = t >> 6;
  int wrow = w >> 1, wcol = w & 1;
  int lg = lane >> 4, lr = lane & 15;
  f32x4 acc[2][2] = {};
  int ldRow = t >> 3;
  int ldCol = (t & 7) * 8;
  for (int k0 = 0; k0 < Kdim; k0 += 64) {
    __syncthreads();
#pragma unroll
    for (int i = 0; i < 2; i++) {
      int r = ldRow + i * 32;
      *reinterpret_cast<uint4*>(&As[r][ldCol]) =
          *reinterpret_cast<const uint4*>(A + (size_t)(m0 + r) * Kdim + k0 + ldCol);
      *reinterpret_cast<uint4*>(&Bs[r][ldCol]) =
          *reinterpret_cast<const uint4*>(Bt + (size_t)(n0 + r) * Kdim + k0 + ldCol);
    }
    __syncthreads();
#pragma unroll
    for (int kk = 0; kk < 2; kk++) {
      bf16x8 a[2], b[2];
#pragma unroll
      for (int i = 0; i < 2; i++) {
        a[i] = *reinterpret_cast<const bf16x8*>(&As[wrow * 32 + i * 16 + lr][kk * 32 + lg * 8]);
        b[i] = *reinterpret_cast<const bf16x8*>(&Bs[wcol * 32 + i * 16 + lr][kk * 32 + lg * 8]);
      }
#pragma unroll
      for (int i = 0; i < 2; i++)
#pragma unroll
        for (int j = 0; j < 2; j++)
          acc[i][j] = __builtin_amdgcn_mfma_f32_16x16x32_bf16(a[i], b[j], acc[i][j], 0, 0, 0);
    }
  }
#pragma unroll
  for (int i = 0; i < 2; i++)
#pragma unroll
    for (int j = 0; j < 2; j++) {
      int col = n0 + wcol * 32 + j * 16 + lr;
#pragma unroll
      for (int r = 0; r < 4; r++) {
        int row = m0 + wrow * 32 + i * 16 + lg * 4 + r;
        float v = acc[i][j][r];
        if (EPI == 1 || EPI == 2 || EPI == 3) v += bias[col];
        if (EPI == 2) v += resid[(size_t)row * N + col];
        if (EPI == 3) v = 0.5f * v * (1.f + erff(v * 0.70710678118654752f));
        if (EPI == 0 || EPI == 3)
          ((__hip_bfloat16*)outp)[(size_t)row * N + col] = __float2bfloat16(v);
        else
          ((float*)outp)[(size_t)row * N + col] = v;
      }
    }
}

// ---------------- repack qkv -> Qb(scaled)/Kb and transposed Vt -------------------------
__global__ __launch_bounds__(256) void repack_qk_kernel(const __hip_bfloat16* __restrict__ qkv,
                                                        __hip_bfloat16* __restrict__ Qb,
                                                        __hip_bfloat16* __restrict__ Kb) {
  int u = blockIdx.x * blockDim.x + threadIdx.x;  // 16384*48 units
  int row = u / 48, seg = u % 48;
  int col = seg * 8;
  int h = col >> 6, d = col & 63;
  int b = row >> 10, n = row & 1023;
  size_t src = (size_t)row * (3 * CDIM);
  size_t dst = (((size_t)(b * NHEAD + h)) * NQ + n) * DHEAD + d;
  union U { uint4 v; __hip_bfloat16 h[8]; };
  U qu, qo;
  qu.v = *reinterpret_cast<const uint4*>(qkv + src + col);
#pragma unroll
  for (int j = 0; j < 8; j++) qo.h[j] = __float2bfloat16(__bfloat162float(qu.h[j]) * 0.125f);
  *reinterpret_cast<uint4*>(Qb + dst) = qo.v;
  *reinterpret_cast<uint4*>(Kb + dst) =
      *reinterpret_cast<const uint4*>(qkv + src + CDIM + col);
}

__global__ void repack_v_kernel(const __hip_bfloat16* __restrict__ qkv,
                                __hip_bfloat16* __restrict__ Vt) {
  __shared__ __hip_bfloat16 tile[32][33];
  int bh = blockIdx.z;
  int b = bh / NHEAD, h = bh % NHEAD;
  int n0 = blockIdx.x * 32, d0 = blockIdx.y * 32;
  int tx = threadIdx.x, ty = threadIdx.y;
#pragma unroll
  for (int i = 0; i < 4; i++) {
    int n = n0 + ty + i * 8;
    tile[ty + i * 8][tx] = qkv[((size_t)(b * NQ + n)) * (3 * CDIM) + 2 * CDIM + h * DHEAD + d0 + tx];
  }
  __syncthreads();
#pragma unroll
  for (int i = 0; i < 4; i++) {
    int d = d0 + ty + i * 8;
    Vt[((size_t)bh * DHEAD + d) * NQ + n0 + tx] = tile[tx][ty + i * 8];
  }
}

// ---------------- flash attention v2: swapped QK^T, in-register P, LDS-staged K/V -------
// block = 4 waves * 32 q-rows = 128 q-rows; KV tiles of 64, double-buffered.
__global__ __launch_bounds__(256) void attn_kernel(const __hip_bfloat16* __restrict__ Qb,
                                                   const __hip_bfloat16* __restrict__ Kb,
                                                   const __hip_bfloat16* __restrict__ Vt,
                                                   __hip_bfloat16* __restrict__ SAb) {
  __shared__ __align__(16) __hip_bfloat16 Ks[2][64][72];
  __shared__ __align__(16) __hip_bfloat16 Vs[2][64][72];
  int bh = blockIdx.x % 96;       // all q-blocks of one (b,h) land on one XCD
  int qblk = blockIdx.x / 96;
  int t = threadIdx.x;
  int w = t >> 6, lane = t & 63;
  int lg = lane >> 4, lr = lane & 15;
  const __hip_bfloat16* Qp = Qb + (size_t)bh * NQ * DHEAD;
  const __hip_bfloat16* Kp = Kb + (size_t)bh * NQ * DHEAD;
  const __hip_bfloat16* Vp = Vt + (size_t)bh * DHEAD * NQ;
  int q0 = qblk * 128 + w * 32;
  // Q fragments (B-operand of swapped QK^T): row=q, k-slice = lg*8
  bf16x8 qf[2][2];
#pragma unroll
  for (int qt = 0; qt < 2; qt++)
#pragma unroll
    for (int kk = 0; kk < 2; kk++)
      qf[qt][kk] = *reinterpret_cast<const bf16x8*>(
          Qp + (size_t)(q0 + qt * 16 + lr) * DHEAD + kk * 32 + lg * 8);
  // staging: wave w stages rows [w*16, w*16+16) of both tiles; 4 lanes/row, 32B/lane
  int srow = w * 16 + (lane >> 2);
  int scol = (lane & 3) * 16;
  uint4 kr0 = *reinterpret_cast<const uint4*>(Kp + (size_t)srow * DHEAD + scol);
  uint4 kr1 = *reinterpret_cast<const uint4*>(Kp + (size_t)srow * DHEAD + scol + 8);
  uint4 vr0 = *reinterpret_cast<const uint4*>(Vp + (size_t)srow * NQ + scol);
  uint4 vr1 = *reinterpret_cast<const uint4*>(Vp + (size_t)srow * NQ + scol + 8);
  *reinterpret_cast<uint4*>(&Ks[0][srow][scol]) = kr0;
  *reinterpret_cast<uint4*>(&Ks[0][srow][scol + 8]) = kr1;
  *reinterpret_cast<uint4*>(&Vs[0][srow][scol]) = vr0;
  *reinterpret_cast<uint4*>(&Vs[0][srow][scol + 8]) = vr1;
  f32x4 o[2][4] = {};
  float m_[2] = {-1e30f, -1e30f};
  float l_[2] = {0.f, 0.f};
  __syncthreads();
  for (int kt = 0; kt < 16; kt++) {
    int cur = kt & 1;
    if (kt < 15) {
      int kb = (kt + 1) * 64;
      kr0 = *reinterpret_cast<const uint4*>(Kp + (size_t)(kb + srow) * DHEAD + scol);
      kr1 = *reinterpret_cast<const uint4*>(Kp + (size_t)(kb + srow) * DHEAD + scol + 8);
      vr0 = *reinterpret_cast<const uint4*>(Vp + (size_t)srow * NQ + kb + scol);
      vr1 = *reinterpret_cast<const uint4*>(Vp + (size_t)srow * NQ + kb + scol + 8);
    }
    // S^T = K @ Q^T : lane holds q=lr, k = kti*16 + lg*4 + r
    f32x4 s[4][2] = {};
#pragma unroll
    for (int kti = 0; kti < 4; kti++)
#pragma unroll
      for (int kk = 0; kk < 2; kk++) {
        bf16x8 a = *reinterpret_cast<const bf16x8*>(&Ks[cur][kti * 16 + lr][kk * 32 + lg * 8]);
#pragma unroll
        for (int qt = 0; qt < 2; qt++)
          s[kti][qt] = __builtin_amdgcn_mfma_f32_16x16x32_bf16(a, qf[qt][kk], s[kti][qt], 0, 0, 0);
      }
    // online softmax: per-lane 16 k-values per q-row, cross-lane via xor16/32
    float corr[2];
#pragma unroll
    for (int qt = 0; qt < 2; qt++) {
      float tm = s[0][qt][0];
#pragma unroll
      for (int kti = 0; kti < 4; kti++)
#pragma unroll
        for (int r = 0; r < 4; r++) tm = fmaxf(tm, s[kti][qt][r]);
      tm = fmaxf(tm, __shfl_xor(tm, 16));
      tm = fmaxf(tm, __shfl_xor(tm, 32));
      float mn = fmaxf(m_[qt], tm);
      corr[qt] = __expf(m_[qt] - mn);
      float ls = 0.f;
#pragma unroll
      for (int kti = 0; kti < 4; kti++)
#pragma unroll
        for (int r = 0; r < 4; r++) {
          float p = __expf(s[kti][qt][r] - mn);
          s[kti][qt][r] = p;
          ls += p;
        }
      ls += __shfl_xor(ls, 16);
      ls += __shfl_xor(ls, 32);
      l_[qt] = l_[qt] * corr[qt] + ls;
      m_[qt] = mn;
    }
    // rescale O (O-layout rows q = lg*4+r : fetch corr from lane lr = lg*4+r)
#pragma unroll
    for (int qt = 0; qt < 2; qt++)
#pragma unroll
      for (int r = 0; r < 4; r++) {
        float cr = __shfl(corr[qt], (lane & 48) | (((lane >> 4) & 3) * 4 + r));
#pragma unroll
        for (int dt = 0; dt < 4; dt++) o[qt][dt][r] *= cr;
      }
    // PV: P already in A-frag layout of 16x16x16 (row=lr=q, k=lg*4+r)
#pragma unroll
    for (int kti = 0; kti < 4; kti++) {
      short4v pa[2];
#pragma unroll
      for (int qt = 0; qt < 2; qt++) {
#pragma unroll
        for (int r = 0; r < 4; r++) {
          __bf16 hv = (__bf16)s[kti][qt][r];
          pa[qt][r] = __builtin_bit_cast(short, hv);
        }
      }
#pragma unroll
      for (int dt = 0; dt < 4; dt++) {
        short4v vb = *reinterpret_cast<const short4v*>(&Vs[cur][dt * 16 + lr][kti * 16 + lg * 4]);
#pragma unroll
        for (int qt = 0; qt < 2; qt++)
          o[qt][dt] = __builtin_amdgcn_mfma_f32_16x16x16bf16_1k(pa[qt], vb, o[qt][dt], 0, 0, 0);
      }
    }
    if (kt < 15) {
      int nb = cur ^ 1;
      *reinterpret_cast<uint4*>(&Ks[nb][srow][scol]) = kr0;
      *reinterpret_cast<uint4*>(&Ks[nb][srow][scol + 8]) = kr1;
      *reinterpret_cast<uint4*>(&Vs[nb][srow][scol]) = vr0;
      *reinterpret_cast<uint4*>(&Vs[nb][srow][scol + 8]) = vr1;
      __syncthreads();
    }
  }
  int b = bh / NHEAD, h = bh % NHEAD;
#pragma unroll
  for (int qt = 0; qt < 2; qt++)
#pragma unroll
    for (int r = 0; r < 4; r++) {
      float li = __shfl(l_[qt], (lane & 48) | (((lane >> 4) & 3) * 4 + r));
      float inv = 1.f / li;
      int row = q0 + qt * 16 + ((lane >> 4) & 3) * 4 + r;
#pragma unroll
      for (int dt = 0; dt < 4; dt++)
        SAb[((size_t)(b * NQ + row)) * CDIM + h * DHEAD + dt * 16 + lr] =
            __float2bfloat16(o[qt][dt][r] * inv);
    }
}

// ---------------- top-K (K=10) nearest of 512 in f64, wave per query --------------------
__global__ __launch_bounds__(256) void topk_kernel(const float* __restrict__ q_pos,
                                                   const float* __restrict__ v_pos,
                                                   int* __restrict__ idxb) {
  int wq = (int)((blockIdx.x * blockDim.x + threadIdx.x) >> 6);
  int lane = threadIdx.x & 63;
  if (wq >= BB * NQ) return;
  int b = wq >> 10;
  const float* qp = q_pos + (size_t)wq * 3;
  double qx = qp[0], qy = qp[1], qz = qp[2];
  double qs = qx * qx + qy * qy + qz * qz;
  double dloc[8];
#pragma unroll
  for (int j = 0; j < 8; j++) {
    int m = lane + 64 * j;
    const float* vp = v_pos + ((size_t)b * MV + m) * 3;
    double vx = vp[0], vy = vp[1], vz = vp[2];
    double vs = vx * vx + vy * vy + vz * vz;
    dloc[j] = qs + vs - 2.0 * (qx * vx + qy * vy + qz * vz);
  }
  for (int k = 0; k < KNN; k++) {
    double best = dloc[0];
    int bj = 0;
#pragma unroll
    for (int j = 1; j < 8; j++)
      if (dloc[j] < best) { best = dloc[j]; bj = j; }
    int bm = lane + 64 * bj;
    for (int off = 1; off < 64; off <<= 1) {
      double od = __shfl_xor(best, off);
      int om = __shfl_xor(bm, off);
      if (od < best || (od == best && om < bm)) { best = od; bm = om; }
    }
    if (lane == 0) idxb[wq * KNN + k] = bm;
#pragma unroll
    for (int j = 0; j < 8; j++)
      if (bm == lane + 64 * j) dloc[j] = 1e300;
  }
}

// ---------------- gather + leaky_relu + max over K + residual ---------------------------
__global__ __launch_bounds__(256) void gather_max_kernel(const float* __restrict__ A1,
                                                         const float* __restrict__ A2,
                                                         const float* __restrict__ q1,
                                                         const int* __restrict__ idxb,
                                                         float* __restrict__ q2) {
  int wq = (int)((blockIdx.x * blockDim.x + threadIdx.x) >> 6);
  int lane = threadIdx.x & 63;
  if (wq >= BB * NQ) return;
  int b = wq >> 10;
  float a2[6], mx[6];
#pragma unroll
  for (int i = 0; i < 6; i++) {
    a2[i] = A2[(size_t)wq * CDIM + lane + 64 * i];
    mx[i] = -1e30f;
  }
  for (int k = 0; k < KNN; k++) {
    int id = idxb[wq * KNN + k];
    const float* a1 = A1 + ((size_t)b * MV + id) * CDIM;
#pragma unroll
    for (int i = 0; i < 6; i++) {
      float g = a1[lane + 64 * i] + a2[i];
      g = g > 0.f ? g : 0.2f * g;
      mx[i] = fmaxf(mx[i], g);
    }
  }
#pragma unroll
  for (int i = 0; i < 6; i++) {
    int c = lane + 64 * i;
    q2[(size_t)wq * CDIM + c] = q1[(size_t)wq * CDIM + c] + mx[i];
  }
}

// ---------------------------------- launcher --------------------------------------------
extern "C" void kernel_launch(void* const* d_in, const int* in_sizes, int n_in,
                              void* d_out, int out_size, void* d_ws, size_t ws_size,
                              hipStream_t stream) {
  const float* q = (const float*)d_in[0];
  const float* v = (const float*)d_in[1];
  const float* q_pos = (const float*)d_in[2];
  const float* v_pos = (const float*)d_in[3];
  const float* norm1_g = (const float*)d_in[4];
  const float* norm1_b = (const float*)d_in[5];
  const float* qkv_w = (const float*)d_in[6];
  const float* proj_w = (const float*)d_in[7];
  const float* proj_b = (const float*)d_in[8];
  const float* normq_g = (const float*)d_in[9];
  const float* normq_b = (const float*)d_in[10];
  const float* normv_g = (const float*)d_in[11];
  const float* normv_b = (const float*)d_in[12];
  const float* knn_w = (const float*)d_in[13];
  const float* knn_b = (const float*)d_in[14];
  const float* norm2_g = (const float*)d_in[15];
  const float* norm2_b = (const float*)d_in[16];
  const float* fc1_w = (const float*)d_in[17];
  const float* fc1_b = (const float*)d_in[18];
  const float* fc2_w = (const float*)d_in[19];
  const float* fc2_b = (const float*)d_in[20];

  char* ws = (char*)d_ws;
  const size_t SZ_Wqkv = (size_t)1152 * 384 * 2;
  const size_t SZ_W384 = (size_t)384 * 384 * 2;
  const size_t SZ_Wfc = (size_t)1536 * 384 * 2;
  const size_t SZ_Xbf = (size_t)16384 * 384 * 2;
  const size_t SZ_QKV = (size_t)16384 * 1152 * 2;
  const size_t SZ_q32 = (size_t)16384 * 384 * 4;
  const size_t SZ_NV = (size_t)8192 * 384 * 2;

  size_t o_Wqkv = 0;
  size_t o_Wproj = o_Wqkv + SZ_Wqkv;
  size_t o_W1 = o_Wproj + SZ_W384;
  size_t o_Wd = o_W1 + SZ_W384;
  size_t o_Wfc1 = o_Wd + SZ_W384;
  size_t o_Wfc2 = o_Wfc1 + SZ_Wfc;
  size_t o_Xbf = o_Wfc2 + SZ_Wfc;
  size_t o_QKV = o_Xbf + SZ_Xbf;       // later reused: A1f (f32) and A2f (f32)
  size_t o_A1 = o_QKV;
  size_t o_A2 = o_QKV + (size_t)8192 * 384 * 4;
  size_t o_Qb = o_QKV + SZ_QKV;
  size_t o_Kb = o_Qb + SZ_Xbf;
  size_t o_Vt = o_Kb + SZ_Xbf;
  size_t o_SA = o_Vt + SZ_Xbf;
  size_t o_H1 = o_Qb;                  // reuse Qb..SA (exactly 16384*1536*2 bytes)
  size_t o_q1 = o_SA + SZ_Xbf;
  size_t o_NV = o_q1 + SZ_q32;
  size_t o_q2 = o_NV + SZ_NV;
  size_t o_idx = o_q2 + SZ_q32;

  __hip_bfloat16* Wqkv_t = (__hip_bfloat16*)(ws + o_Wqkv);
  __hip_bfloat16* Wproj_t = (__hip_bfloat16*)(ws + o_Wproj);
  __hip_bfloat16* W1_t = (__hip_bfloat16*)(ws + o_W1);
  __hip_bfloat16* Wd_t = (__hip_bfloat16*)(ws + o_Wd);
  __hip_bfloat16* Wfc1_t = (__hip_bfloat16*)(ws + o_Wfc1);
  __hip_bfloat16* Wfc2_t = (__hip_bfloat16*)(ws + o_Wfc2);
  __hip_bfloat16* Xbf = (__hip_bfloat16*)(ws + o_Xbf);
  __hip_bfloat16* QKVb = (__hip_bfloat16*)(ws + o_QKV);
  float* A1f = (float*)(ws + o_A1);
  float* A2f = (float*)(ws + o_A2);
  __hip_bfloat16* Qb = (__hip_bfloat16*)(ws + o_Qb);
  __hip_bfloat16* Kb = (__hip_bfloat16*)(ws + o_Kb);
  __hip_bfloat16* Vt = (__hip_bfloat16*)(ws + o_Vt);
  __hip_bfloat16* SAb = (__hip_bfloat16*)(ws + o_SA);
  __hip_bfloat16* H1 = (__hip_bfloat16*)(ws + o_H1);
  float* q1 = (float*)(ws + o_q1);
  __hip_bfloat16* NV = (__hip_bfloat16*)(ws + o_NV);
  float* q2 = (float*)(ws + o_q2);
  int* idxb = (int*)(ws + o_idx);
  float* outf = (float*)d_out;

  dim3 b32x8(32, 8);
  // 1. weights
  cast_t_kernel<<<dim3(12, 36), b32x8, 0, stream>>>(qkv_w, Wqkv_t, 384, 1152);
  cast_t_kernel<<<dim3(12, 12), b32x8, 0, stream>>>(proj_w, Wproj_t, 384, 384);
  cast_t_knn_kernel<<<dim3(12, 12), b32x8, 0, stream>>>(knn_w, W1_t, Wd_t);
  cast_t_kernel<<<dim3(12, 48), b32x8, 0, stream>>>(fc1_w, Wfc1_t, 384, 1536);
  cast_t_kernel<<<dim3(48, 12), b32x8, 0, stream>>>(fc2_w, Wfc2_t, 1536, 384);
  // 2. LN1(q)
  ln_kernel<<<4096, 256, 0, stream>>>(q, norm1_g, norm1_b, Xbf, 16384);
  // 3. qkv gemm
  gemm_kernel<0><<<dim3(18, 256), 256, 0, stream>>>(Xbf, Wqkv_t, nullptr, nullptr, QKVb,
                                                    16384, 1152, 384);
  // 4. repack
  repack_qk_kernel<<<3072, 256, 0, stream>>>(QKVb, Qb, Kb);
  repack_v_kernel<<<dim3(32, 2, 96), b32x8, 0, stream>>>(QKVb, Vt);
  // 5. attention (768 blocks = 96 bh * 8 q-blocks)
  attn_kernel<<<768, 256, 0, stream>>>(Qb, Kb, Vt, SAb);
  // 6. proj + bias + residual(q) -> q1
  gemm_kernel<2><<<dim3(6, 256), 256, 0, stream>>>(SAb, Wproj_t, proj_b, q, q1, 16384, 384, 384);
  // 7. LN(q1)->NQ(Xbf), LN(v)->NV
  ln_kernel<<<4096, 256, 0, stream>>>(q1, normq_g, normq_b, Xbf, 16384);
  ln_kernel<<<2048, 256, 0, stream>>>(v, normv_g, normv_b, NV, 8192);
  // 8. A1 = NV@W1
  gemm_kernel<4><<<dim3(6, 128), 256, 0, stream>>>(NV, W1_t, nullptr, nullptr, A1f, 8192, 384, 384);
  // 9. A2 = NQ@Wd + knn_b
  gemm_kernel<1><<<dim3(6, 256), 256, 0, stream>>>(Xbf, Wd_t, knn_b, nullptr, A2f, 16384, 384, 384);
  // 10. top-k
  topk_kernel<<<4096, 256, 0, stream>>>(q_pos, v_pos, idxb);
  // 11. gather/max/residual -> q2
  gather_max_kernel<<<4096, 256, 0, stream>>>(A1f, A2f, q1, idxb, q2);
  // 12. LN2(q2)->Xbf
  ln_kernel<<<4096, 256, 0, stream>>>(q2, norm2_g, norm2_b, Xbf, 16384);
  // 13. fc1 + gelu -> H1
  gemm_kernel<3><<<dim3(24, 256), 256, 0, stream>>>(Xbf, Wfc1_t, fc1_b, nullptr, H1,
                                                    16384, 1536, 384);
  // 14. fc2 + bias + residual(q2) -> out
  gemm_kernel<2><<<dim3(6, 256), 256, 0, stream>>>(H1, Wfc2_t, fc2_b, q2, outf, 16384, 384, 1536);
}

// Round 3
// 357.463 us; speedup vs baseline: 1.4406x; 1.0311x over previous
//
#include <hip/hip_runtime.h>
#include <hip/hip_bf16.h>

#define CDIM 384
#define NHEAD 6
#define DHEAD 64
#define BB 16
#define NQ 1024
#define MV 512
#define HIDD 1536
#define KNN 10

typedef __attribute__((ext_vector_type(8))) __bf16 bf16x8;
typedef __attribute__((ext_vector_type(4))) float f32x4;
typedef __attribute__((ext_vector_type(4))) short short4v;

// ---------------- weight transpose-cast: Wt[n][k] = W[k][n] (f32 -> bf16) ----------------
__global__ void cast_t_kernel(const float* __restrict__ W, __hip_bfloat16* __restrict__ Wt,
                              int Kd, int Nd) {
  __shared__ float tile[32][33];
  int k0 = blockIdx.x * 32, n0 = blockIdx.y * 32;
  int tx = threadIdx.x, ty = threadIdx.y;
#pragma unroll
  for (int i = 0; i < 4; i++)
    tile[ty + i * 8][tx] = W[(size_t)(k0 + ty + i * 8) * Nd + n0 + tx];
  __syncthreads();
#pragma unroll
  for (int i = 0; i < 4; i++)
    Wt[(size_t)(n0 + ty + i * 8) * Kd + k0 + tx] = __float2bfloat16(tile[tx][ty + i * 8]);
}

// knn_w (768x384): W1t[n][k]=knn[k][n]; Wdt[n][k]=knn[384+k][n]-knn[k][n]
__global__ void cast_t_knn_kernel(const float* __restrict__ Wk,
                                  __hip_bfloat16* __restrict__ W1t,
                                  __hip_bfloat16* __restrict__ Wdt) {
  __shared__ float t1[32][33];
  __shared__ float t2[32][33];
  int k0 = blockIdx.x * 32, n0 = blockIdx.y * 32;
  int tx = threadIdx.x, ty = threadIdx.y;
#pragma unroll
  for (int i = 0; i < 4; i++) {
    int k = k0 + ty + i * 8;
    float w1 = Wk[(size_t)k * CDIM + n0 + tx];
    float w2 = Wk[(size_t)(CDIM + k) * CDIM + n0 + tx];
    t1[ty + i * 8][tx] = w1;
    t2[ty + i * 8][tx] = w2 - w1;
  }
  __syncthreads();
#pragma unroll
  for (int i = 0; i < 4; i++) {
    W1t[(size_t)(n0 + ty + i * 8) * CDIM + k0 + tx] = __float2bfloat16(t1[tx][ty + i * 8]);
    Wdt[(size_t)(n0 + ty + i * 8) * CDIM + k0 + tx] = __float2bfloat16(t2[tx][ty + i * 8]);
  }
}

// ---------------- LayerNorm: f32 in -> bf16 out, 384 cols, one wave per row -------------
__global__ __launch_bounds__(256) void ln_kernel(const float* __restrict__ x,
                                                 const float* __restrict__ gw,
                                                 const float* __restrict__ bw,
                                                 __hip_bfloat16* __restrict__ out, int rows) {
  int wave = (int)((blockIdx.x * blockDim.x + threadIdx.x) >> 6);
  int lane = threadIdx.x & 63;
  if (wave >= rows) return;
  const float* xr = x + (size_t)wave * CDIM;
  float v0[6];
  float s = 0.f;
#pragma unroll
  for (int i = 0; i < 3; i++) {
    float2 t = *reinterpret_cast<const float2*>(xr + i * 128 + lane * 2);
    v0[i * 2] = t.x; v0[i * 2 + 1] = t.y; s += t.x + t.y;
  }
  for (int off = 32; off; off >>= 1) s += __shfl_xor(s, off);
  float mean = s * (1.f / 384.f);
  float sq = 0.f;
#pragma unroll
  for (int i = 0; i < 6; i++) { float d = v0[i] - mean; sq += d * d; }
  for (int off = 32; off; off >>= 1) sq += __shfl_xor(sq, off);
  float rstd = rsqrtf(sq * (1.f / 384.f) + 1e-5f);
#pragma unroll
  for (int i = 0; i < 3; i++) {
    int c = i * 128 + lane * 2;
    float2 gg = *reinterpret_cast<const float2*>(gw + c);
    float2 bb = *reinterpret_cast<const float2*>(bw + c);
    float o0 = (v0[i * 2] - mean) * rstd * gg.x + bb.x;
    float o1 = (v0[i * 2 + 1] - mean) * rstd * gg.y + bb.y;
    __hip_bfloat162 p;
    p.x = __float2bfloat16(o0); p.y = __float2bfloat16(o1);
    *reinterpret_cast<__hip_bfloat162*>(out + (size_t)wave * CDIM + c) = p;
  }
}

// ---------------- bf16 GEMM, 128x128 tile, BK=64, global_load_lds + XOR swizzle ---------
// A (MxK) @ Bt (NxK)^T. 4 waves, each computes a 64x64 quadrant (4x4 16x16 frags).
// LDS linear [128][64]; source pre-swizzled so read slot' = slot ^ (row&7) is conflict-free.
// EPI: 0 ->bf16 | 1 bias->f32 | 2 bias+resid->f32 | 3 bias+gelu->bf16 | 4 ->f32
//      5 fused qkv scatter: outp=Qb(scaled), out2=Kb, out3=Vt(transposed)
template <int EPI>
__global__ __launch_bounds__(256) void gemm_kernel(const __hip_bfloat16* __restrict__ A,
                                                   const __hip_bfloat16* __restrict__ Bt,
                                                   const float* __restrict__ bias,
                                                   const float* __restrict__ resid,
                                                   void* __restrict__ outp,
                                                   void* __restrict__ out2,
                                                   void* __restrict__ out3,
                                                   int M, int N, int Kdim) {
  __shared__ __align__(16) __hip_bfloat16 As[128 * 64];
  __shared__ __align__(16) __hip_bfloat16 Bs[128 * 64];
  int m0 = blockIdx.y * 128, n0 = blockIdx.x * 128;
  int t = threadIdx.x;
  int lane = t & 63, w = t >> 6;
  int wrow = w >> 1, wcol = w & 1;
  int lg = lane >> 4, lr = lane & 15;
  // staging: instruction i covers 8 rows (i*4+w)*8 .. +8; lane -> row += lane>>3,
  // 16B slot (lane&7). Global k-slot pre-swizzled: (lane&7) ^ (row&7) = (lane&7)^(lane>>3).
  int gcol = (((lane & 7) ^ (lane >> 3)) * 8);
  const __hip_bfloat16* Ab = A + (size_t)(m0 + w * 8 + (lane >> 3)) * Kdim + gcol;
  const __hip_bfloat16* Bb = Bt + (size_t)(n0 + w * 8 + (lane >> 3)) * Kdim + gcol;
  char* AsB = (char*)As;
  char* BsB = (char*)Bs;
  f32x4 acc[4][4] = {};
  for (int k0 = 0; k0 < Kdim; k0 += 64) {
    if (k0) __syncthreads();
#pragma unroll
    for (int i = 0; i < 4; i++)
      __builtin_amdgcn_global_load_lds(
          (const __attribute__((address_space(1))) void*)(Ab + (size_t)(i * 32) * Kdim + k0),
          (__attribute__((address_space(3))) void*)(AsB + (i * 4 + w) * 1024), 16, 0, 0);
#pragma unroll
    for (int i = 0; i < 4; i++)
      __builtin_amdgcn_global_load_lds(
          (const __attribute__((address_space(1))) void*)(Bb + (size_t)(i * 32) * Kdim + k0),
          (__attribute__((address_space(3))) void*)(BsB + (i * 4 + w) * 1024), 16, 0, 0);
    __syncthreads();  // compiler drains vmcnt before s_barrier
#pragma unroll
    for (int kk = 0; kk < 2; kk++) {
      bf16x8 a[4], b[4];
#pragma unroll
      for (int i = 0; i < 4; i++) {
        int ra = wrow * 64 + i * 16 + lr;
        int rb = wcol * 64 + i * 16 + lr;
        int sw = (((kk << 2) | lg) ^ (lr & 7)) * 16;
        a[i] = *reinterpret_cast<const bf16x8*>(AsB + ra * 128 + sw);
        b[i] = *reinterpret_cast<const bf16x8*>(BsB + rb * 128 + sw);
      }
#pragma unroll
      for (int i = 0; i < 4; i++)
#pragma unroll
        for (int j = 0; j < 4; j++)
          acc[i][j] = __builtin_amdgcn_mfma_f32_16x16x32_bf16(a[i], b[j], acc[i][j], 0, 0, 0);
    }
  }
#pragma unroll
  for (int i = 0; i < 4; i++)
#pragma unroll
    for (int j = 0; j < 4; j++) {
      int col = n0 + wcol * 64 + j * 16 + lr;
#pragma unroll
      for (int r = 0; r < 4; r++) {
        int row = m0 + wrow * 64 + i * 16 + lg * 4 + r;
        float v = acc[i][j][r];
        if (EPI == 5) {
          int b = row >> 10, n = row & 1023;
          if (col < CDIM) {
            int h = col >> 6, d = col & 63;
            ((__hip_bfloat16*)outp)[(((size_t)(b * NHEAD + h)) * NQ + n) * DHEAD + d] =
                __float2bfloat16(v * 0.125f);
          } else if (col < 2 * CDIM) {
            int c = col - CDIM, h = c >> 6, d = c & 63;
            ((__hip_bfloat16*)out2)[(((size_t)(b * NHEAD + h)) * NQ + n) * DHEAD + d] =
                __float2bfloat16(v);
          } else {
            int c = col - 2 * CDIM, h = c >> 6, d = c & 63;
            ((__hip_bfloat16*)out3)[(((size_t)(b * NHEAD + h)) * DHEAD + d) * NQ + n] =
                __float2bfloat16(v);
          }
        } else {
          if (EPI == 1 || EPI == 2 || EPI == 3) v += bias[col];
          if (EPI == 2) v += resid[(size_t)row * N + col];
          if (EPI == 3) v = 0.5f * v * (1.f + erff(v * 0.70710678118654752f));
          if (EPI == 0 || EPI == 3)
            ((__hip_bfloat16*)outp)[(size_t)row * N + col] = __float2bfloat16(v);
          else
            ((float*)outp)[(size_t)row * N + col] = v;
        }
      }
    }
}

// ---------------- flash attention: swapped QK^T, in-register P, LDS-staged K/V ----------
__global__ __launch_bounds__(256) void attn_kernel(const __hip_bfloat16* __restrict__ Qb,
                                                   const __hip_bfloat16* __restrict__ Kb,
                                                   const __hip_bfloat16* __restrict__ Vt,
                                                   __hip_bfloat16* __restrict__ SAb) {
  __shared__ __align__(16) __hip_bfloat16 Ks[2][64][72];
  __shared__ __align__(16) __hip_bfloat16 Vs[2][64][72];
  int bh = blockIdx.x % 96;
  int qblk = blockIdx.x / 96;
  int t = threadIdx.x;
  int w = t >> 6, lane = t & 63;
  int lg = lane >> 4, lr = lane & 15;
  const __hip_bfloat16* Qp = Qb + (size_t)bh * NQ * DHEAD;
  const __hip_bfloat16* Kp = Kb + (size_t)bh * NQ * DHEAD;
  const __hip_bfloat16* Vp = Vt + (size_t)bh * DHEAD * NQ;
  int q0 = qblk * 128 + w * 32;
  bf16x8 qf[2][2];
#pragma unroll
  for (int qt = 0; qt < 2; qt++)
#pragma unroll
    for (int kk = 0; kk < 2; kk++)
      qf[qt][kk] = *reinterpret_cast<const bf16x8*>(
          Qp + (size_t)(q0 + qt * 16 + lr) * DHEAD + kk * 32 + lg * 8);
  int srow = w * 16 + (lane >> 2);
  int scol = (lane & 3) * 16;
  uint4 kr0 = *reinterpret_cast<const uint4*>(Kp + (size_t)srow * DHEAD + scol);
  uint4 kr1 = *reinterpret_cast<const uint4*>(Kp + (size_t)srow * DHEAD + scol + 8);
  uint4 vr0 = *reinterpret_cast<const uint4*>(Vp + (size_t)srow * NQ + scol);
  uint4 vr1 = *reinterpret_cast<const uint4*>(Vp + (size_t)srow * NQ + scol + 8);
  *reinterpret_cast<uint4*>(&Ks[0][srow][scol]) = kr0;
  *reinterpret_cast<uint4*>(&Ks[0][srow][scol + 8]) = kr1;
  *reinterpret_cast<uint4*>(&Vs[0][srow][scol]) = vr0;
  *reinterpret_cast<uint4*>(&Vs[0][srow][scol + 8]) = vr1;
  f32x4 o[2][4] = {};
  float m_[2] = {-1e30f, -1e30f};
  float l_[2] = {0.f, 0.f};
  __syncthreads();
  for (int kt = 0; kt < 16; kt++) {
    int cur = kt & 1;
    if (kt < 15) {
      int kb = (kt + 1) * 64;
      kr0 = *reinterpret_cast<const uint4*>(Kp + (size_t)(kb + srow) * DHEAD + scol);
      kr1 = *reinterpret_cast<const uint4*>(Kp + (size_t)(kb + srow) * DHEAD + scol + 8);
      vr0 = *reinterpret_cast<const uint4*>(Vp + (size_t)srow * NQ + kb + scol);
      vr1 = *reinterpret_cast<const uint4*>(Vp + (size_t)srow * NQ + kb + scol + 8);
    }
    f32x4 s[4][2] = {};
#pragma unroll
    for (int kti = 0; kti < 4; kti++)
#pragma unroll
      for (int kk = 0; kk < 2; kk++) {
        bf16x8 a = *reinterpret_cast<const bf16x8*>(&Ks[cur][kti * 16 + lr][kk * 32 + lg * 8]);
#pragma unroll
        for (int qt = 0; qt < 2; qt++)
          s[kti][qt] = __builtin_amdgcn_mfma_f32_16x16x32_bf16(a, qf[qt][kk], s[kti][qt], 0, 0, 0);
      }
    float corr[2];
#pragma unroll
    for (int qt = 0; qt < 2; qt++) {
      float tm = s[0][qt][0];
#pragma unroll
      for (int kti = 0; kti < 4; kti++)
#pragma unroll
        for (int r = 0; r < 4; r++) tm = fmaxf(tm, s[kti][qt][r]);
      tm = fmaxf(tm, __shfl_xor(tm, 16));
      tm = fmaxf(tm, __shfl_xor(tm, 32));
      float mn = fmaxf(m_[qt], tm);
      corr[qt] = __expf(m_[qt] - mn);
      float ls = 0.f;
#pragma unroll
      for (int kti = 0; kti < 4; kti++)
#pragma unroll
        for (int r = 0; r < 4; r++) {
          float p = __expf(s[kti][qt][r] - mn);
          s[kti][qt][r] = p;
          ls += p;
        }
      ls += __shfl_xor(ls, 16);
      ls += __shfl_xor(ls, 32);
      l_[qt] = l_[qt] * corr[qt] + ls;
      m_[qt] = mn;
    }
#pragma unroll
    for (int qt = 0; qt < 2; qt++)
#pragma unroll
      for (int r = 0; r < 4; r++) {
        float cr = __shfl(corr[qt], (lane & 48) | (((lane >> 4) & 3) * 4 + r));
#pragma unroll
        for (int dt = 0; dt < 4; dt++) o[qt][dt][r] *= cr;
      }
#pragma unroll
    for (int kti = 0; kti < 4; kti++) {
      short4v pa[2];
#pragma unroll
      for (int qt = 0; qt < 2; qt++) {
#pragma unroll
        for (int r = 0; r < 4; r++) {
          __bf16 hv = (__bf16)s[kti][qt][r];
          pa[qt][r] = __builtin_bit_cast(short, hv);
        }
      }
#pragma unroll
      for (int dt = 0; dt < 4; dt++) {
        short4v vb = *reinterpret_cast<const short4v*>(&Vs[cur][dt * 16 + lr][kti * 16 + lg * 4]);
#pragma unroll
        for (int qt = 0; qt < 2; qt++)
          o[qt][dt] = __builtin_amdgcn_mfma_f32_16x16x16bf16_1k(pa[qt], vb, o[qt][dt], 0, 0, 0);
      }
    }
    if (kt < 15) {
      int nb = cur ^ 1;
      *reinterpret_cast<uint4*>(&Ks[nb][srow][scol]) = kr0;
      *reinterpret_cast<uint4*>(&Ks[nb][srow][scol + 8]) = kr1;
      *reinterpret_cast<uint4*>(&Vs[nb][srow][scol]) = vr0;
      *reinterpret_cast<uint4*>(&Vs[nb][srow][scol + 8]) = vr1;
      __syncthreads();
    }
  }
  int b = bh / NHEAD, h = bh % NHEAD;
#pragma unroll
  for (int qt = 0; qt < 2; qt++)
#pragma unroll
    for (int r = 0; r < 4; r++) {
      float li = __shfl(l_[qt], (lane & 48) | (((lane >> 4) & 3) * 4 + r));
      float inv = 1.f / li;
      int row = q0 + qt * 16 + ((lane >> 4) & 3) * 4 + r;
#pragma unroll
      for (int dt = 0; dt < 4; dt++)
        SAb[((size_t)(b * NQ + row)) * CDIM + h * DHEAD + dt * 16 + lr] =
            __float2bfloat16(o[qt][dt][r] * inv);
    }
}

// ------- fused: top-K (f64) + gather/leaky/max + residual + LN2 -> q2 (f32) & xout (bf16)
__global__ __launch_bounds__(256) void knn_fused_kernel(const float* __restrict__ q_pos,
                                                        const float* __restrict__ v_pos,
                                                        const float* __restrict__ A1,
                                                        const float* __restrict__ A2,
                                                        const float* __restrict__ q1,
                                                        const float* __restrict__ g2,
                                                        const float* __restrict__ b2,
                                                        float* __restrict__ q2,
                                                        __hip_bfloat16* __restrict__ xout) {
  int wq = (int)((blockIdx.x * blockDim.x + threadIdx.x) >> 6);
  int lane = threadIdx.x & 63;
  if (wq >= BB * NQ) return;
  int b = wq >> 10;
  const float* qp = q_pos + (size_t)wq * 3;
  double qx = qp[0], qy = qp[1], qz = qp[2];
  double qs = qx * qx + qy * qy + qz * qz;
  double dloc[8];
#pragma unroll
  for (int j = 0; j < 8; j++) {
    int m = lane + 64 * j;
    const float* vp = v_pos + ((size_t)b * MV + m) * 3;
    double vx = vp[0], vy = vp[1], vz = vp[2];
    double vs = vx * vx + vy * vy + vz * vz;
    dloc[j] = qs + vs - 2.0 * (qx * vx + qy * vy + qz * vz);
  }
  float a2[6], mx[6];
#pragma unroll
  for (int i = 0; i < 6; i++) {
    a2[i] = A2[(size_t)wq * CDIM + lane + 64 * i];
    mx[i] = -1e30f;
  }
  for (int k = 0; k < KNN; k++) {
    double best = dloc[0];
    int bj = 0;
#pragma unroll
    for (int j = 1; j < 8; j++)
      if (dloc[j] < best) { best = dloc[j]; bj = j; }
    int bm = lane + 64 * bj;
    for (int off = 1; off < 64; off <<= 1) {
      double od = __shfl_xor(best, off);
      int om = __shfl_xor(bm, off);
      if (od < best || (od == best && om < bm)) { best = od; bm = om; }
    }
    const float* a1 = A1 + ((size_t)b * MV + bm) * CDIM;
#pragma unroll
    for (int i = 0; i < 6; i++) {
      float g = a1[lane + 64 * i] + a2[i];
      g = g > 0.f ? g : 0.2f * g;
      mx[i] = fmaxf(mx[i], g);
    }
#pragma unroll
    for (int j = 0; j < 8; j++)
      if (bm == lane + 64 * j) dloc[j] = 1e300;
  }
  // q2 = q1 + mx, then LN2 in-wave
  float vals[6];
  float s = 0.f;
#pragma unroll
  for (int i = 0; i < 6; i++) {
    vals[i] = q1[(size_t)wq * CDIM + lane + 64 * i] + mx[i];
    s += vals[i];
  }
  for (int off = 32; off; off >>= 1) s += __shfl_xor(s, off);
  float mean = s * (1.f / 384.f);
  float sq = 0.f;
#pragma unroll
  for (int i = 0; i < 6; i++) { float d = vals[i] - mean; sq += d * d; }
  for (int off = 32; off; off >>= 1) sq += __shfl_xor(sq, off);
  float rstd = rsqrtf(sq * (1.f / 384.f) + 1e-5f);
#pragma unroll
  for (int i = 0; i < 6; i++) {
    int c = lane + 64 * i;
    q2[(size_t)wq * CDIM + c] = vals[i];
    xout[(size_t)wq * CDIM + c] = __float2bfloat16((vals[i] - mean) * rstd * g2[c] + b2[c]);
  }
}

// ---------------------------------- launcher --------------------------------------------
extern "C" void kernel_launch(void* const* d_in, const int* in_sizes, int n_in,
                              void* d_out, int out_size, void* d_ws, size_t ws_size,
                              hipStream_t stream) {
  const float* q = (const float*)d_in[0];
  const float* v = (const float*)d_in[1];
  const float* q_pos = (const float*)d_in[2];
  const float* v_pos = (const float*)d_in[3];
  const float* norm1_g = (const float*)d_in[4];
  const float* norm1_b = (const float*)d_in[5];
  const float* qkv_w = (const float*)d_in[6];
  const float* proj_w = (const float*)d_in[7];
  const float* proj_b = (const float*)d_in[8];
  const float* normq_g = (const float*)d_in[9];
  const float* normq_b = (const float*)d_in[10];
  const float* normv_g = (const float*)d_in[11];
  const float* normv_b = (const float*)d_in[12];
  const float* knn_w = (const float*)d_in[13];
  const float* knn_b = (const float*)d_in[14];
  const float* norm2_g = (const float*)d_in[15];
  const float* norm2_b = (const float*)d_in[16];
  const float* fc1_w = (const float*)d_in[17];
  const float* fc1_b = (const float*)d_in[18];
  const float* fc2_w = (const float*)d_in[19];
  const float* fc2_b = (const float*)d_in[20];

  char* ws = (char*)d_ws;
  const size_t SZ_Wqkv = (size_t)1152 * 384 * 2;
  const size_t SZ_W384 = (size_t)384 * 384 * 2;
  const size_t SZ_Wfc = (size_t)1536 * 384 * 2;
  const size_t SZ_Xbf = (size_t)16384 * 384 * 2;
  const size_t SZ_QKV = (size_t)16384 * 1152 * 2;
  const size_t SZ_q32 = (size_t)16384 * 384 * 4;
  const size_t SZ_NV = (size_t)8192 * 384 * 2;

  size_t o_Wqkv = 0;
  size_t o_Wproj = o_Wqkv + SZ_Wqkv;
  size_t o_W1 = o_Wproj + SZ_W384;
  size_t o_Wd = o_W1 + SZ_W384;
  size_t o_Wfc1 = o_Wd + SZ_W384;
  size_t o_Wfc2 = o_Wfc1 + SZ_Wfc;
  size_t o_Xbf = o_Wfc2 + SZ_Wfc;
  size_t o_QKV = o_Xbf + SZ_Xbf;       // region reused: A1f (f32) and A2f (f32)
  size_t o_A1 = o_QKV;
  size_t o_A2 = o_QKV + (size_t)8192 * 384 * 4;
  size_t o_Qb = o_QKV + SZ_QKV;
  size_t o_Kb = o_Qb + SZ_Xbf;
  size_t o_Vt = o_Kb + SZ_Xbf;
  size_t o_SA = o_Vt + SZ_Xbf;
  size_t o_H1 = o_Qb;                  // reuse Qb..SA (exactly 16384*1536*2 bytes)
  size_t o_q1 = o_SA + SZ_Xbf;
  size_t o_NV = o_q1 + SZ_q32;
  size_t o_q2 = o_NV + SZ_NV;

  __hip_bfloat16* Wqkv_t = (__hip_bfloat16*)(ws + o_Wqkv);
  __hip_bfloat16* Wproj_t = (__hip_bfloat16*)(ws + o_Wproj);
  __hip_bfloat16* W1_t = (__hip_bfloat16*)(ws + o_W1);
  __hip_bfloat16* Wd_t = (__hip_bfloat16*)(ws + o_Wd);
  __hip_bfloat16* Wfc1_t = (__hip_bfloat16*)(ws + o_Wfc1);
  __hip_bfloat16* Wfc2_t = (__hip_bfloat16*)(ws + o_Wfc2);
  __hip_bfloat16* Xbf = (__hip_bfloat16*)(ws + o_Xbf);
  float* A1f = (float*)(ws + o_A1);
  float* A2f = (float*)(ws + o_A2);
  __hip_bfloat16* Qb = (__hip_bfloat16*)(ws + o_Qb);
  __hip_bfloat16* Kb = (__hip_bfloat16*)(ws + o_Kb);
  __hip_bfloat16* Vt = (__hip_bfloat16*)(ws + o_Vt);
  __hip_bfloat16* SAb = (__hip_bfloat16*)(ws + o_SA);
  __hip_bfloat16* H1 = (__hip_bfloat16*)(ws + o_H1);
  float* q1 = (float*)(ws + o_q1);
  __hip_bfloat16* NV = (__hip_bfloat16*)(ws + o_NV);
  float* q2 = (float*)(ws + o_q2);
  float* outf = (float*)d_out;

  dim3 b32x8(32, 8);
  // 1. weights
  cast_t_kernel<<<dim3(12, 36), b32x8, 0, stream>>>(qkv_w, Wqkv_t, 384, 1152);
  cast_t_kernel<<<dim3(12, 12), b32x8, 0, stream>>>(proj_w, Wproj_t, 384, 384);
  cast_t_knn_kernel<<<dim3(12, 12), b32x8, 0, stream>>>(knn_w, W1_t, Wd_t);
  cast_t_kernel<<<dim3(12, 48), b32x8, 0, stream>>>(fc1_w, Wfc1_t, 384, 1536);
  cast_t_kernel<<<dim3(48, 12), b32x8, 0, stream>>>(fc2_w, Wfc2_t, 1536, 384);
  // 2. LN1(q)
  ln_kernel<<<4096, 256, 0, stream>>>(q, norm1_g, norm1_b, Xbf, 16384);
  // 3. qkv gemm fused with head repack (Qb scaled, Kb, Vt transposed)
  gemm_kernel<5><<<dim3(9, 128), 256, 0, stream>>>(Xbf, Wqkv_t, nullptr, nullptr,
                                                   Qb, Kb, Vt, 16384, 1152, 384);
  // 4. attention (768 blocks = 96 bh * 8 q-blocks)
  attn_kernel<<<768, 256, 0, stream>>>(Qb, Kb, Vt, SAb);
  // 5. proj + bias + residual(q) -> q1
  gemm_kernel<2><<<dim3(3, 128), 256, 0, stream>>>(SAb, Wproj_t, proj_b, q, q1,
                                                   nullptr, nullptr, 16384, 384, 384);
  // 6. LN(q1)->Xbf, LN(v)->NV
  ln_kernel<<<4096, 256, 0, stream>>>(q1, normq_g, normq_b, Xbf, 16384);
  ln_kernel<<<2048, 256, 0, stream>>>(v, normv_g, normv_b, NV, 8192);
  // 7. A1 = NV@W1 ; A2 = NQ@Wd + knn_b
  gemm_kernel<4><<<dim3(3, 64), 256, 0, stream>>>(NV, W1_t, nullptr, nullptr, A1f,
                                                  nullptr, nullptr, 8192, 384, 384);
  gemm_kernel<1><<<dim3(3, 128), 256, 0, stream>>>(Xbf, Wd_t, knn_b, nullptr, A2f,
                                                   nullptr, nullptr, 16384, 384, 384);
  // 8. fused topk + gather/max + residual + LN2 -> q2, Xbf
  knn_fused_kernel<<<4096, 256, 0, stream>>>(q_pos, v_pos, A1f, A2f, q1,
                                             norm2_g, norm2_b, q2, Xbf);
  // 9. fc1 + gelu -> H1
  gemm_kernel<3><<<dim3(12, 128), 256, 0, stream>>>(Xbf, Wfc1_t, fc1_b, nullptr, H1,
                                                    nullptr, nullptr, 16384, 1536, 384);
  // 10. fc2 + bias + residual(q2) -> out
  gemm_kernel<2><<<dim3(3, 128), 256, 0, stream>>>(H1, Wfc2_t, fc2_b, q2, outf,
                                                   nullptr, nullptr, 16384, 384, 1536);
}